// Round 2
// baseline (1168.344 us; speedup 1.0000x reference)
//
#include <hip/hip_runtime.h>

#define C_IN  32
#define C_OUT 64
#define KK    27
#define RB    128      // output rows per bucket (RB*C_OUT*4 = 32 KB LDS)

// ===========================================================================
// Fallback path (round-1 kernels) in case ws_size is too small
// ===========================================================================
__global__ __launch_bounds__(256) void sic_init_bias(float4* __restrict__ out4,
                                                     const float4* __restrict__ bias4,
                                                     int total4) {
    int idx    = blockIdx.x * 256 + threadIdx.x;
    int stride = gridDim.x * 256;
    for (int i = idx; i < total4; i += stride) out4[i] = bias4[i & 15];
}

__global__ __launch_bounds__(256) void sic_scatter(
    const float* __restrict__ feats, const float* __restrict__ weight,
    const int* __restrict__ bwd, const int* __restrict__ in_idx,
    const int* __restrict__ out_idx, float* __restrict__ out, int n_in)
{
    const int k = blockIdx.y, lane = threadIdx.x & 63, wid = threadIdx.x >> 6;
    float w[C_IN];
    const float* wk = weight + k * (C_IN * C_OUT);
#pragma unroll
    for (int i = 0; i < C_IN; ++i) w[i] = wk[i * C_OUT + lane];
    const int waves_total = gridDim.x * 4;
    const long long base = (long long)k * n_in;
    for (int p = blockIdx.x * 4 + wid; p < n_in; p += waves_total) {
        int src = __builtin_amdgcn_readfirstlane(in_idx[base + p]);
        int dst = __builtin_amdgcn_readfirstlane(out_idx[base + p]);
        int row = __builtin_amdgcn_readfirstlane(bwd[src]);
        const float* f = feats + (long long)row * C_IN;
        float acc = 0.0f;
#pragma unroll
        for (int i = 0; i < C_IN; ++i) acc = fmaf(f[i], w[i], acc);
        atomicAdd(out + (long long)dst * C_OUT + lane, acc);
    }
}

// ===========================================================================
// Main path: bucket-privatized gather/accumulate (no global atomics hot path)
// ===========================================================================
__global__ __launch_bounds__(512) void sic_zero(int* __restrict__ p, int n) {
    int i = blockIdx.x * 512 + threadIdx.x;
    int stride = gridDim.x * 512;
    for (; i < n; i += stride) p[i] = 0;
}

// histogram of (bucket, k) sub-lists
__global__ __launch_bounds__(256) void sic_hist(const int* __restrict__ out_idx,
                                                int* __restrict__ count, int n_in) {
    int k = blockIdx.y;
    int p = blockIdx.x * 256 + threadIdx.x;
    if (p < n_in) {
        int dst = out_idx[(size_t)k * n_in + p];
        atomicAdd(&count[(dst >> 7) * KK + k], 1);
    }
}

// chunked exclusive scan, step 1: per-chunk scan + chunk sums
__global__ __launch_bounds__(512) void sic_scan1(const int* __restrict__ count,
                                                 int* __restrict__ startv,
                                                 int* __restrict__ sums, int n) {
    __shared__ int sm[512];
    int tid = threadIdx.x;
    int g = blockIdx.x * 512 + tid;
    int e = (g < n) ? count[g] : 0;
    sm[tid] = e;
    __syncthreads();
    for (int off = 1; off < 512; off <<= 1) {
        int t = (tid >= off) ? sm[tid - off] : 0;
        __syncthreads();
        sm[tid] += t;
        __syncthreads();
    }
    if (g < n) startv[g] = sm[tid] - e;          // exclusive within chunk
    if (tid == 511) sums[blockIdx.x] = sm[511];  // chunk total
}

// step 2: scan of chunk sums (NCH <= 512)
__global__ __launch_bounds__(512) void sic_scan2(int* __restrict__ sums, int n) {
    __shared__ int sm[512];
    int tid = threadIdx.x;
    int e = (tid < n) ? sums[tid] : 0;
    sm[tid] = e;
    __syncthreads();
    for (int off = 1; off < 512; off <<= 1) {
        int t = (tid >= off) ? sm[tid - off] : 0;
        __syncthreads();
        sm[tid] += t;
        __syncthreads();
    }
    if (tid < n) sums[tid] = sm[tid] - e;        // exclusive
}

// step 3: add chunk offsets; materialize start and cursor
__global__ __launch_bounds__(512) void sic_scan3(int* __restrict__ startv,
                                                 int* __restrict__ cursor,
                                                 const int* __restrict__ sums, int n) {
    int g = blockIdx.x * 512 + threadIdx.x;
    if (g < n) {
        int v = startv[g] + sums[blockIdx.x];
        startv[g] = v;
        cursor[g] = v;
    }
}

// scatter packed records (src_row<<7 | dst_low) into sub-bucket lists
__global__ __launch_bounds__(256) void sic_fill(const int* __restrict__ in_idx,
                                                const int* __restrict__ out_idx,
                                                const int* __restrict__ bwd,
                                                int* __restrict__ cursor,
                                                unsigned int* __restrict__ recs,
                                                int n_in) {
    int k = blockIdx.y;
    int p = blockIdx.x * 256 + threadIdx.x;
    if (p < n_in) {
        size_t base = (size_t)k * n_in + p;
        int dst = out_idx[base];
        int src = in_idx[base];
        int row = bwd[src];   // fuse the feats[bwd] gather into the record
        int pos = atomicAdd(&cursor[(dst >> 7) * KK + k], 1);
        recs[pos] = ((unsigned int)row << 7) | (unsigned int)(dst & (RB - 1));
    }
}

// per-bucket accumulate in LDS, single coalesced write-out with bias
__global__ __launch_bounds__(512) void sic_accum(
    const unsigned int* __restrict__ recs,
    const int* __restrict__ startv,
    const int* __restrict__ count,
    const float* __restrict__ feats,
    const float* __restrict__ weight,
    const float* __restrict__ bias,
    float* __restrict__ out, int n_out)
{
    __shared__ __align__(16) float acc[RB * C_OUT];  // 32 KB
    const int tid = threadIdx.x;
    for (int i = tid; i < RB * C_OUT; i += 512) acc[i] = 0.0f;
    __syncthreads();

    const int lane = tid & 63;
    const int wid  = tid >> 6;     // 0..7
    const int b    = blockIdx.x;

    for (int kk = wid; kk < KK; kk += 8) {
        // W[kk][0..31][lane] pinned in 32 VGPRs (coalesced 256B wave loads, L2-hot)
        float w[C_IN];
        const float* wk = weight + kk * (C_IN * C_OUT);
#pragma unroll
        for (int i = 0; i < C_IN; ++i) w[i] = wk[i * C_OUT + lane];

        const int sb = b * KK + kk;
        int s = __builtin_amdgcn_readfirstlane(startv[sb]);
        int c = __builtin_amdgcn_readfirstlane(count[sb]);
        for (int j = 0; j < c; ++j) {
            unsigned int rec = __builtin_amdgcn_readfirstlane(recs[s + j]);
            const float* f = feats + (size_t)(rec >> 7) * C_IN;  // wave-uniform -> s_load
            float a = 0.0f;
#pragma unroll
            for (int i = 0; i < C_IN; ++i) a = fmaf(f[i], w[i], a);
            atomicAdd(&acc[(rec & (RB - 1)) * C_OUT + lane], a);  // ds_add_f32
        }
    }
    __syncthreads();

    // write-out: 2048 float4s per bucket, bias fused
    const float4* acc4   = (const float4*)acc;
    const float4* bias4v = (const float4*)bias;
    float4*       out4   = (float4*)out;
    for (int t = tid; t < RB * C_OUT / 4; t += 512) {
        int row = b * RB + (t >> 4);
        if (row < n_out) {
            float4 v = acc4[t];
            float4 bb = bias4v[t & 15];
            v.x += bb.x; v.y += bb.y; v.z += bb.z; v.w += bb.w;
            out4[(size_t)b * (RB * C_OUT / 4) + t] = v;
        }
    }
}

// ===========================================================================
extern "C" void kernel_launch(void* const* d_in, const int* in_sizes, int n_in_cnt,
                              void* d_out, int out_size, void* d_ws, size_t ws_size,
                              hipStream_t stream) {
    const float* feats   = (const float*)d_in[0];
    const float* weight  = (const float*)d_in[1];
    const float* bias    = (const float*)d_in[2];
    const int*   bwd     = (const int*)d_in[3];
    const int*   in_idx  = (const int*)d_in[4];
    const int*   out_idx = (const int*)d_in[5];
    float*       out     = (float*)d_out;

    const int n_in  = in_sizes[0] / C_IN;     // 100000
    const int n_out = out_size / C_OUT;       // 800000
    const int NB    = (n_out + RB - 1) / RB;  // 6250 buckets
    const int NSB   = NB * KK;                // 168750 sub-lists
    const int NCH   = (NSB + 511) / 512;      // 330 scan chunks
    const size_t P  = (size_t)KK * n_in;      // 2.7M pairs

    int* ws = (int*)d_ws;
    size_t need_ints = (size_t)3 * NSB + ((NCH + 255) & ~255) + P;
    if (ws_size < need_ints * sizeof(int) || NCH > 512) {
        // fallback: round-1 atomic path
        const int total4 = out_size / 4;
        hipLaunchKernelGGL(sic_init_bias, dim3(2048), dim3(256), 0, stream,
                           (float4*)out, (const float4*)bias, total4);
        hipLaunchKernelGGL(sic_scatter, dim3(160, KK), dim3(256), 0, stream,
                           feats, weight, bwd, in_idx, out_idx, out, n_in);
        return;
    }

    int* count  = ws;
    int* startv = ws + NSB;
    int* cursor = ws + 2 * (size_t)NSB;
    int* sums   = ws + 3 * (size_t)NSB;
    unsigned int* recs = (unsigned int*)(ws + 3 * (size_t)NSB + ((NCH + 255) & ~255));

    dim3 gpair((n_in + 255) / 256, KK);

    hipLaunchKernelGGL(sic_zero,  dim3(330), dim3(512), 0, stream, count, NSB);
    hipLaunchKernelGGL(sic_hist,  gpair, dim3(256), 0, stream, out_idx, count, n_in);
    hipLaunchKernelGGL(sic_scan1, dim3(NCH), dim3(512), 0, stream, count, startv, sums, NSB);
    hipLaunchKernelGGL(sic_scan2, dim3(1),   dim3(512), 0, stream, sums, NCH);
    hipLaunchKernelGGL(sic_scan3, dim3(NCH), dim3(512), 0, stream, startv, cursor, sums, NSB);
    hipLaunchKernelGGL(sic_fill,  gpair, dim3(256), 0, stream,
                       in_idx, out_idx, bwd, cursor, recs, n_in);
    hipLaunchKernelGGL(sic_accum, dim3(NB), dim3(512), 0, stream,
                       recs, startv, count, feats, weight, bias, out, n_out);
}